// Round 6
// baseline (203.140 us; speedup 1.0000x reference)
//
#include <hip/hip_runtime.h>

#define NN 100000      // nodes
#define DD 128         // embedding dim
#define KE 300         // raw feature dim
#define KP 320         // padded K for enc
#define NE 1600000     // edges
#define NB 4096        // batch (users)
#define HL 50          // history length
#define CL 20          // candidates

#define NBUCK 1563     // ceil(NN/64): buckets of 64 dst nodes
#define SLOT  1280     // max edges/bucket (mean 1024, sigma 32, +8 sigma)
#define PBLK  250      // partition blocks
#define EPB   6400     // edges per partition block
#define EPT   25       // edges per thread

typedef unsigned short ushort_t;
using bf16x8 = __attribute__((ext_vector_type(8))) short;
using f32x4  = __attribute__((ext_vector_type(4))) float;

union U4B { uint4 u; bf16x8 b; unsigned a[4]; };

__device__ __forceinline__ ushort_t f2bf(float f) {
    unsigned u = __float_as_uint(f);
    unsigned r = u + 0x7FFF + ((u >> 16) & 1);   // RNE
    return (ushort_t)(r >> 16);
}
__device__ __forceinline__ float bf2f(unsigned s) {
    return __uint_as_float(s << 16);
}

// ---------------- weight prep: transpose + convert to bf16 ------------------
__global__ __launch_bounds__(256) void prep_w(const float* __restrict__ We,
                                              const float* __restrict__ Wg,
                                              ushort_t* __restrict__ wte,
                                              ushort_t* __restrict__ wtg) {
    int i = blockIdx.x * 256 + threadIdx.x;
    if (i < 128 * KP) {
        int n = i / KP, k = i - n * KP;
        float v = (k < KE) ? We[k * DD + n] : 0.f;
        wte[n * KP + k] = f2bf(v);
    } else if (i < 128 * KP + 128 * 128) {
        int j = i - 128 * KP;
        int n = j >> 7, k = j & 127;
        wtg[n * DD + k] = f2bf(Wg[k * DD + n]);
    }
}

// ---- A fragment loader: 8 consecutive fp32 -> bf16x8 (zero past edges) -----
__device__ __forceinline__ bf16x8 loadA8(const float* __restrict__ x,
                                         int row, int col, bool rowok) {
    float v[8];
    if (rowok && col + 8 <= KE) {
        const float4* p = (const float4*)&x[(long long)row * KE + col];
        float4 a = p[0], b = p[1];
        v[0]=a.x; v[1]=a.y; v[2]=a.z; v[3]=a.w;
        v[4]=b.x; v[5]=b.y; v[6]=b.z; v[7]=b.w;
    } else {
#pragma unroll
        for (int j = 0; j < 8; ++j) {
            int c = col + j;
            v[j] = (rowok && c < KE) ? x[(long long)row * KE + c] : 0.f;
        }
    }
    U4B r;
#pragma unroll
    for (int j = 0; j < 4; ++j)
        r.a[j] = (unsigned)f2bf(v[2*j]) | ((unsigned)f2bf(v[2*j+1]) << 16);
    return r.b;
}

// ---------------- encoder: news_bf = bf16( x @ Wenc ) -----------------------
// B 64-K chunk in frag-major LDS (16 KB); A streamed global->regs, no A-LDS.
__global__ __launch_bounds__(256) void enc_mfma(const float* __restrict__ x,
                                                const ushort_t* __restrict__ wt,
                                                ushort_t* __restrict__ news) {
    __shared__ ushort_t BsF[2 * 8 * 64 * 8];   // [ks][cf][lane][8] = 16 KB
    const int tid = threadIdx.x;
    const int w = tid >> 6, lane = tid & 63;
    const int hl = lane & 15, kg = lane >> 4;
    const int row0 = blockIdx.x * 128 + w * 32;
    const int r0 = row0 + hl, r1 = row0 + 16 + hl;
    const bool ok0 = r0 < NN, ok1 = r1 < NN;

    f32x4 acc[2][8];
#pragma unroll
    for (int i = 0; i < 2; ++i)
#pragma unroll
        for (int j = 0; j < 8; ++j) acc[i][j] = (f32x4)0.f;

    for (int p = 0; p < 5; ++p) {
        const int k0 = p * 64;
        // A fragments direct from global (independent of LDS)
        bf16x8 a00 = loadA8(x, r0, k0 + kg * 8, ok0);
        bf16x8 a10 = loadA8(x, r1, k0 + kg * 8, ok1);
        bf16x8 a01 = loadA8(x, r0, k0 + 32 + kg * 8, ok0);
        bf16x8 a11 = loadA8(x, r1, k0 + 32 + kg * 8, ok1);
        // stage B chunk (1024 16B tuples, 4/thread)
#pragma unroll
        for (int i = 0; i < 4; ++i) {
            int t = tid + i * 256;
            int ks = t >> 9, cf = (t >> 6) & 7, ln = t & 63;
            uint4 v = *(const uint4*)&wt[(cf * 16 + (ln & 15)) * KP +
                                         k0 + ks * 32 + ((ln >> 4) & 3) * 8];
            *(uint4*)&BsF[t * 8] = v;
        }
        __syncthreads();
#pragma unroll
        for (int ks = 0; ks < 2; ++ks) {
            bf16x8 af0 = ks ? a01 : a00;
            bf16x8 af1 = ks ? a11 : a10;
#pragma unroll
            for (int cf = 0; cf < 8; ++cf) {
                bf16x8 bfr = *(const bf16x8*)&BsF[((ks * 8 + cf) * 64 + lane) * 8];
                acc[0][cf] = __builtin_amdgcn_mfma_f32_16x16x32_bf16(af0, bfr, acc[0][cf], 0, 0, 0);
                acc[1][cf] = __builtin_amdgcn_mfma_f32_16x16x32_bf16(af1, bfr, acc[1][cf], 0, 0, 0);
            }
        }
        __syncthreads();
    }
#pragma unroll
    for (int rf = 0; rf < 2; ++rf)
#pragma unroll
        for (int cf = 0; cf < 8; ++cf)
#pragma unroll
            for (int j = 0; j < 4; ++j) {
                int grow = row0 + rf * 16 + kg * 4 + j;
                int gcol = cf * 16 + hl;
                if (grow < NN)
                    news[(long long)grow * DD + gcol] = f2bf(acc[rf][cf][j]);
            }
}

// ---------------- partition: edges -> 1563 buckets of 64 dsts ---------------
// Packed entry: (src << 6) | (dst & 63). Per-block contiguous runs per bucket.
__global__ __launch_bounds__(256) void k_part(const int* __restrict__ ei,
                                              unsigned* __restrict__ gcur,
                                              unsigned* __restrict__ pairs) {
    __shared__ unsigned hist[NBUCK], rbase[NBUCK], lcur[NBUCK];
    const int tid = threadIdx.x;
    const int eb = blockIdx.x * EPB;

    for (int i = tid; i < NBUCK; i += 256) hist[i] = 0;
    __syncthreads();

    unsigned val[EPT], bk[EPT];
#pragma unroll
    for (int l = 0; l < EPT; ++l) {
        int e = eb + l * 256 + tid;
        unsigned src = (unsigned)ei[e];
        unsigned dst = (unsigned)ei[NE + e];
        val[l] = (src << 6) | (dst & 63u);
        bk[l] = dst >> 6;
        atomicAdd(&hist[bk[l]], 1u);
    }
    __syncthreads();

    for (int i = tid; i < NBUCK; i += 256) {
        unsigned h = hist[i];
        rbase[i] = (unsigned)i * SLOT + (h ? atomicAdd(&gcur[i], h) : 0u);
        lcur[i] = 0;
    }
    __syncthreads();

#pragma unroll
    for (int l = 0; l < EPT; ++l) {
        unsigned b = bk[l];
        unsigned pos = rbase[b] + atomicAdd(&lcur[b], 1u);
        if (pos < (b + 1u) * SLOT) pairs[pos] = val[l];   // overflow guard
    }
}

// ---------------- bucket aggregate: 64-dst LDS CSR + register gather --------
__global__ __launch_bounds__(256) void k_bagg(const unsigned* __restrict__ gcur,
                                              const unsigned* __restrict__ pairs,
                                              const ushort_t* __restrict__ news,
                                              ushort_t* __restrict__ agg,
                                              int* __restrict__ deg) {
    __shared__ unsigned srcs[SLOT];
    __shared__ unsigned hist[64], base[64], cur[64];
    const int tid = threadIdx.x;
    const int b = blockIdx.x;
    int cnt = (int)gcur[b];
    if (cnt > SLOT) cnt = SLOT;

    if (tid < 64) hist[tid] = 0;
    __syncthreads();
    for (int i = tid; i < cnt; i += 256)
        atomicAdd(&hist[pairs[b * SLOT + i] & 63u], 1u);
    __syncthreads();

    // single-wave exclusive scan of 64 bins (no barriers inside)
    if (tid < 64) {
        unsigned h = hist[tid], v = h;
#pragma unroll
        for (int off = 1; off < 64; off <<= 1) {
            unsigned n = __shfl_up(v, off);
            if (tid >= off) v += n;
        }
        base[tid] = v - h;
        cur[tid]  = v - h;
    }
    __syncthreads();

    for (int i = tid; i < cnt; i += 256) {
        unsigned v = pairs[b * SLOT + i];
        srcs[atomicAdd(&cur[v & 63u], 1u)] = v >> 6;
    }
    __syncthreads();

    // wave per dst: 4 edges in flight, 16B/lane gathers, register accum
    const int w = tid >> 6, lane = tid & 63;
    const int e = lane >> 4, l = lane & 15;
    for (int d = w; d < 64; d += 4) {
        int gd = b * 64 + d;
        if (gd >= NN) break;                 // uniform per wave
        int s0 = (int)base[d], c = (int)hist[d];
        float acc[8];
#pragma unroll
        for (int j = 0; j < 8; ++j) acc[j] = 0.f;
        for (int i = 0; i < c; i += 4) {
            int ii = i + e;
            uint4 v = make_uint4(0u, 0u, 0u, 0u);
            if (ii < c) {
                unsigned src = srcs[s0 + ii];
                v = *(const uint4*)&news[(long long)src * DD + l * 8];
            }
            acc[0] += bf2f(v.x & 0xFFFFu); acc[1] += bf2f(v.x >> 16);
            acc[2] += bf2f(v.y & 0xFFFFu); acc[3] += bf2f(v.y >> 16);
            acc[4] += bf2f(v.z & 0xFFFFu); acc[5] += bf2f(v.z >> 16);
            acc[6] += bf2f(v.w & 0xFFFFu); acc[7] += bf2f(v.w >> 16);
        }
#pragma unroll
        for (int j = 0; j < 8; ++j) {
            acc[j] += __shfl_xor(acc[j], 16);
            acc[j] += __shfl_xor(acc[j], 32);
        }
        if (e == 0) {
            uint4 o;
            o.x = (unsigned)f2bf(acc[0]) | ((unsigned)f2bf(acc[1]) << 16);
            o.y = (unsigned)f2bf(acc[2]) | ((unsigned)f2bf(acc[3]) << 16);
            o.z = (unsigned)f2bf(acc[4]) | ((unsigned)f2bf(acc[5]) << 16);
            o.w = (unsigned)f2bf(acc[6]) | ((unsigned)f2bf(acc[7]) << 16);
            *(uint4*)&agg[(long long)gd * DD + l * 8] = o;
            if (l == 0) deg[gd] = c;
        }
    }
}

// ---------------- gnn: xx = f32(news) + (agg @ Wgnn) / deg ------------------
// Whole B (32 KB) in frag-major LDS once; A-frags direct from global.
__global__ __launch_bounds__(256) void gnn_mfma(const ushort_t* __restrict__ aggb,
                                                const ushort_t* __restrict__ wt,
                                                const int* __restrict__ deg,
                                                const ushort_t* __restrict__ newsb,
                                                float* __restrict__ xx) {
    __shared__ ushort_t BsF[4 * 8 * 64 * 8];   // [ks][cf][lane][8] = 32 KB
    const int tid = threadIdx.x;
    const int w = tid >> 6, lane = tid & 63;
    const int hl = lane & 15, kg = lane >> 4;
    const int row0 = blockIdx.x * 128 + w * 32;
    const int r0 = row0 + hl, r1 = row0 + 16 + hl;
    const bool ok0 = r0 < NN, ok1 = r1 < NN;

    // stage all of B (2048 16B tuples, 8/thread)
#pragma unroll
    for (int i = 0; i < 8; ++i) {
        int t = tid + i * 256;
        int ks = t >> 9, cf = (t >> 6) & 7, ln = t & 63;
        uint4 v = *(const uint4*)&wt[(cf * 16 + (ln & 15)) * DD +
                                     ks * 32 + ((ln >> 4) & 3) * 8];
        *(uint4*)&BsF[t * 8] = v;
    }
    // A fragments (8 x 16B loads) — overlap with staging
    U4B a0[4], a1[4];
#pragma unroll
    for (int ks = 0; ks < 4; ++ks) {
        a0[ks].u = ok0 ? *(const uint4*)&aggb[(long long)r0 * DD + ks * 32 + kg * 8]
                       : make_uint4(0, 0, 0, 0);
        a1[ks].u = ok1 ? *(const uint4*)&aggb[(long long)r1 * DD + ks * 32 + kg * 8]
                       : make_uint4(0, 0, 0, 0);
    }
    f32x4 acc[2][8];
#pragma unroll
    for (int i = 0; i < 2; ++i)
#pragma unroll
        for (int j = 0; j < 8; ++j) acc[i][j] = (f32x4)0.f;

    __syncthreads();
#pragma unroll
    for (int ks = 0; ks < 4; ++ks)
#pragma unroll
        for (int cf = 0; cf < 8; ++cf) {
            bf16x8 bfr = *(const bf16x8*)&BsF[((ks * 8 + cf) * 64 + lane) * 8];
            acc[0][cf] = __builtin_amdgcn_mfma_f32_16x16x32_bf16(a0[ks].b, bfr, acc[0][cf], 0, 0, 0);
            acc[1][cf] = __builtin_amdgcn_mfma_f32_16x16x32_bf16(a1[ks].b, bfr, acc[1][cf], 0, 0, 0);
        }

#pragma unroll
    for (int rf = 0; rf < 2; ++rf) {
        int grow0 = row0 + rf * 16 + kg * 4;
#pragma unroll
        for (int j = 0; j < 4; ++j) {
            int grow = grow0 + j;
            if (grow < NN) {
                float s = 1.f / fmaxf((float)deg[grow], 1.f);
#pragma unroll
                for (int cf = 0; cf < 8; ++cf) {
                    int gcol = cf * 16 + hl;
                    float nv = bf2f((unsigned)newsb[(long long)grow * DD + gcol]);
                    xx[(long long)grow * DD + gcol] = nv + acc[rf][cf][j] * s;
                }
            }
        }
    }
}

// ---------------- user vector: mean of masked history embeddings ------------
__global__ __launch_bounds__(128) void user_vec_k(const int* __restrict__ hist,
                                                  const float* __restrict__ xx,
                                                  float* __restrict__ uv) {
    int b = blockIdx.x, t = threadIdx.x;
    float s = 0.f, cnt = 0.f;
    for (int h = 0; h < HL; ++h) {
        int id = hist[b * HL + h];
        if (id != 0) { s += xx[(long long)id * DD + t]; cnt += 1.f; }
    }
    uv[b * DD + t] = s / fmaxf(cnt, 1e-9f);
}

// ---------------- scores: dot(cand_emb, user_vec) ---------------------------
__global__ __launch_bounds__(64) void scores_k(const int* __restrict__ cand,
                                               const float* __restrict__ xx,
                                               const float* __restrict__ uv,
                                               float* __restrict__ out) {
    int b = blockIdx.x, t = threadIdx.x;
    float u0 = uv[b * DD + t];
    float u1 = uv[b * DD + 64 + t];
    for (int c = 0; c < CL; ++c) {
        int id = cand[b * CL + c];
        float p = u0 * xx[(long long)id * DD + t] +
                  u1 * xx[(long long)id * DD + 64 + t];
#pragma unroll
        for (int off = 32; off >= 1; off >>= 1) p += __shfl_xor(p, off);
        if (t == 0) out[b * CL + c] = p;
    }
}

extern "C" void kernel_launch(void* const* d_in, const int* in_sizes, int n_in,
                              void* d_out, int out_size, void* d_ws, size_t ws_size,
                              hipStream_t stream) {
    const float* x    = (const float*)d_in[0];
    // d_in[1] = n_id == arange(N) -> identity scatter, unused
    const int*   ei   = (const int*)d_in[2];
    const int*   hist = (const int*)d_in[3];
    const int*   cand = (const int*)d_in[4];
    const float* Wenc = (const float*)d_in[5];
    const float* Wgnn = (const float*)d_in[6];
    float* out = (float*)d_out;

    float*    xx      = (float*)d_ws;                      // [NN*DD] f32
    float*    uv      = xx + (size_t)NN * DD;              // [NB*DD] f32
    ushort_t* news_bf = (ushort_t*)(uv + (size_t)NB * DD); // [NN*DD] bf16
    ushort_t* agg_bf  = news_bf + (size_t)NN * DD;         // [NN*DD] bf16
    ushort_t* wt_enc  = agg_bf + (size_t)NN * DD;          // [128*KP]
    ushort_t* wt_gnn  = wt_enc + 128 * KP;                 // [128*128]
    int*      deg     = (int*)(wt_gnn + 128 * 128);        // [NN]
    unsigned* gcur    = (unsigned*)(deg + NN);             // [NBUCK]
    unsigned* pairs   = gcur + NBUCK;                      // [NBUCK*SLOT]

    hipMemsetAsync(gcur, 0, NBUCK * sizeof(unsigned), stream);

    prep_w<<<(128 * KP + 128 * 128 + 255) / 256, 256, 0, stream>>>(Wenc, Wgnn, wt_enc, wt_gnn);
    enc_mfma<<<(NN + 127) / 128, 256, 0, stream>>>(x, wt_enc, news_bf);

    k_part<<<PBLK, 256, 0, stream>>>(ei, gcur, pairs);
    k_bagg<<<NBUCK, 256, 0, stream>>>(gcur, pairs, news_bf, agg_bf, deg);

    gnn_mfma<<<(NN + 127) / 128, 256, 0, stream>>>(agg_bf, wt_gnn, deg, news_bf, xx);
    user_vec_k<<<NB, 128, 0, stream>>>(hist, xx, uv);
    scores_k<<<NB, 64, 0, stream>>>(cand, xx, uv, out);
}